// Round 8
// baseline (929.459 us; speedup 1.0000x reference)
//
#include <hip/hip_runtime.h>
#include <hip/hip_bf16.h>
#include <cstdint>

#define USER_NUM 30000
#define ITEM_NUM 70000
#define NTOT     100000   // USER_NUM + ITEM_NUM

typedef __attribute__((ext_vector_type(8))) short bf16x8;
typedef __attribute__((ext_vector_type(8))) ushort u16x8;
typedef __attribute__((ext_vector_type(4))) float f32x4;

// fp32 -> (hi, lo) bf16 pair via truncation; a ~= hi + lo to ~2^-16 rel.
__device__ __forceinline__ void split2(float x, ushort& h, ushort& l) {
    unsigned u = __builtin_bit_cast(unsigned int, x);
    h = (ushort)(u >> 16);
    float hf = __builtin_bit_cast(float, u & 0xffff0000u);
    float lo = x - hf;
    l = (ushort)(__builtin_bit_cast(unsigned int, lo) >> 16);
}

// ---------------------------------------------------------------------------
// CSR build kernels
// ---------------------------------------------------------------------------

__global__ void hist_rows(const int* __restrict__ erow, int* __restrict__ counts, int nnz) {
    int i = blockIdx.x * blockDim.x + threadIdx.x;
    if (i < nnz) atomicAdd(&counts[erow[i]], 1);
}

__global__ void scan_block(const int* __restrict__ counts, int* __restrict__ row_ptr,
                           int* __restrict__ blk_sums, int n) {
    __shared__ int sd[1024];
    int i = blockIdx.x * 1024 + threadIdx.x;
    int v = (i < n) ? counts[i] : 0;
    sd[threadIdx.x] = v;
    __syncthreads();
    for (int off = 1; off < 1024; off <<= 1) {
        int t = (threadIdx.x >= off) ? sd[threadIdx.x - off] : 0;
        __syncthreads();
        sd[threadIdx.x] += t;
        __syncthreads();
    }
    if (i < n) row_ptr[i] = sd[threadIdx.x] - v;   // block-local exclusive
    if (threadIdx.x == 1023) blk_sums[blockIdx.x] = sd[1023];
}

__global__ void scan_sums(int* __restrict__ blk_sums, int nb) {
    __shared__ int sd[128];
    int v = (threadIdx.x < nb) ? blk_sums[threadIdx.x] : 0;
    sd[threadIdx.x] = v;
    __syncthreads();
    for (int off = 1; off < 128; off <<= 1) {
        int t = (threadIdx.x >= off) ? sd[threadIdx.x - off] : 0;
        __syncthreads();
        sd[threadIdx.x] += t;
        __syncthreads();
    }
    if (threadIdx.x < nb) blk_sums[threadIdx.x] = sd[threadIdx.x] - v;  // exclusive
}

__global__ void scan_add(int* __restrict__ row_ptr, const int* __restrict__ blk_sums,
                         int n, int nnz) {
    int i = blockIdx.x * 1024 + threadIdx.x;
    if (i < n) row_ptr[i] += blk_sums[blockIdx.x];
    if (blockIdx.x == 0 && threadIdx.x == 0) row_ptr[n] = nnz;
}

__global__ void scatter_edges(const int* __restrict__ erow, const int* __restrict__ ecol,
                              const float* __restrict__ eval,
                              const int* __restrict__ row_ptr, int* __restrict__ fill,
                              int* __restrict__ scol, float* __restrict__ sval, int nnz) {
    int i = blockIdx.x * blockDim.x + threadIdx.x;
    if (i >= nnz) return;
    int r = erow[i];
    int pos = row_ptr[r] + atomicAdd(&fill[r], 1);
    scol[pos] = ecol[i];
    sval[pos] = eval[i];
}

// ---------------------------------------------------------------------------
// Pre-split a weight matrix into hi/lo bf16 arrays (done once per launch).
// ---------------------------------------------------------------------------

__global__ void split_w(const float* __restrict__ W, ushort* __restrict__ Wh,
                        ushort* __restrict__ Wl, int n) {
    int i = blockIdx.x * blockDim.x + threadIdx.x;
    if (i >= n) return;
    ushort h, l;
    split2(W[i], h, l);
    Wh[i] = h;
    Wl[i] = l;
}

// ---------------------------------------------------------------------------
// Dual split-bf16 MFMA GEMM — DIRECT-REGISTER version (no LDS, no barriers):
//   C1 = A @ W1^T + b1 + b2 ;  C2 = (A @ W1^T) + (A*A) @ W2^T
// A = virtual row-concat [xa ; xb] split at `split`, rows length KK.
// Block 256 = 4 independent waves; wave tile 32 rows x TN cols; BK=32.
// Each wave's A-fragment rows are wave-exclusive, so lanes load A straight
// from global (16 rows x 128 B per b128 pair, coalesced; L2/L3 absorbs the
// grid.x re-read), convert hi/lo + square in registers, MFMA. Zero
// __syncthreads -> all 16 waves/CU free-run; compiler schedules loads across
// iterations. W fragments from global (same addrs across blocks -> L1-hot).
// ---------------------------------------------------------------------------

template <int TN, int KK>
__global__ __launch_bounds__(256, 4)
void gemm_dual_direct(const float* __restrict__ xa, const float* __restrict__ xb, int split,
                      const ushort* __restrict__ W1h, const ushort* __restrict__ W1l,
                      const ushort* __restrict__ W2h, const ushort* __restrict__ W2l,
                      const float* __restrict__ bias1, const float* __restrict__ bias2,
                      float* __restrict__ C1, float* __restrict__ C2,
                      int M, int Nout) {
    constexpr int BK = 32;
    constexpr int NITER = KK / BK;
    constexpr int NI = TN / 16;
    constexpr int MI = 2;                  // 32 rows per wave

    const int m0 = blockIdx.y * 128;
    const int n0 = blockIdx.x * TN;
    const int t  = threadIdx.x;
    const int lane = t & 63, w = t >> 6;
    const int lm = lane & 15, lq = lane >> 4;

    // per-lane A source rows (clamped; OOB masked in epilogue)
    const float* arow[MI];
#pragma unroll
    for (int mi = 0; mi < MI; ++mi) {
        int gm = m0 + w * 32 + mi * 16 + lm;
        const float* rp = xa;
        if (gm < M) rp = (gm < split) ? xa + (size_t)gm * KK
                                      : xb + (size_t)(gm - split) * KK;
        arow[mi] = rp + lq * 8;
    }

    f32x4 acc1[MI][NI] = {};
    f32x4 acc2[MI][NI] = {};

#pragma unroll 2
    for (int it = 0; it < NITER; ++it) {
#pragma unroll
        for (int mi = 0; mi < MI; ++mi) {
            const float* p = arow[mi] + it * BK;
            float4 x0 = *(const float4*)p;
            float4 x1 = *(const float4*)(p + 4);
            float f[8] = {x0.x, x0.y, x0.z, x0.w, x1.x, x1.y, x1.z, x1.w};
            ushort ah[8], al[8], qh[8], ql[8];
#pragma unroll
            for (int j = 0; j < 8; ++j) {
                split2(f[j], ah[j], al[j]);
                float sq = f[j] * f[j];
                split2(sq, qh[j], ql[j]);
            }
            bf16x8 vah = *(const bf16x8*)ah;
            bf16x8 vgl = *(const bf16x8*)al;
            bf16x8 vqh = *(const bf16x8*)qh;
            bf16x8 vql = *(const bf16x8*)ql;
#pragma unroll
            for (int ni = 0; ni < NI; ++ni) {
                size_t wo = (size_t)(n0 + ni * 16 + lm) * KK + it * BK + lq * 8;
                bf16x8 b1h = *(const bf16x8*)(W1h + wo);
                bf16x8 b1l = *(const bf16x8*)(W1l + wo);
                bf16x8 b2h = *(const bf16x8*)(W2h + wo);
                bf16x8 b2l = *(const bf16x8*)(W2l + wo);
                acc1[mi][ni] = __builtin_amdgcn_mfma_f32_16x16x32_bf16(vah, b1h, acc1[mi][ni], 0, 0, 0);
                acc1[mi][ni] = __builtin_amdgcn_mfma_f32_16x16x32_bf16(vah, b1l, acc1[mi][ni], 0, 0, 0);
                acc1[mi][ni] = __builtin_amdgcn_mfma_f32_16x16x32_bf16(vgl, b1h, acc1[mi][ni], 0, 0, 0);
                acc2[mi][ni] = __builtin_amdgcn_mfma_f32_16x16x32_bf16(vqh, b2h, acc2[mi][ni], 0, 0, 0);
                acc2[mi][ni] = __builtin_amdgcn_mfma_f32_16x16x32_bf16(vqh, b2l, acc2[mi][ni], 0, 0, 0);
                acc2[mi][ni] = __builtin_amdgcn_mfma_f32_16x16x32_bf16(vql, b2h, acc2[mi][ni], 0, 0, 0);
            }
        }
    }

    // ---- epilogue: C/D layout col=lane&15, row=lq*4+r; biases folded into C1 ----
#pragma unroll
    for (int mi = 0; mi < MI; ++mi)
#pragma unroll
        for (int ni = 0; ni < NI; ++ni)
#pragma unroll
            for (int r = 0; r < 4; ++r) {
                int gm = m0 + w * 32 + mi * 16 + lq * 4 + r;
                int gn = n0 + ni * 16 + lm;
                if (gm < M && gn < Nout) {
                    size_t o = (size_t)gm * Nout + gn;
                    float g1 = acc1[mi][ni][r];
                    C1[o] = g1 + bias1[gn] + bias2[gn];
                    C2[o] = g1 + acc2[mi][ni][r];
                }
            }
}

// ---------------------------------------------------------------------------
// T1 GEMM with fused gather (known-good R6 structure):
//   e1 = relu( [final[u] ; final[it+U]] @ T1_W^T + T1_b ),  K = 896
// ---------------------------------------------------------------------------

template <int TN, int KK>
__global__ __launch_bounds__(256, 4)
void gemm_t1_mfma(const int* __restrict__ userIdx, const int* __restrict__ itemIdx,
                  const float* __restrict__ uEmbd, const float* __restrict__ iEmbd,
                  const float* __restrict__ f1, const float* __restrict__ f2,
                  const ushort* __restrict__ Wh, const ushort* __restrict__ Wl,
                  const float* __restrict__ bias, float* __restrict__ C,
                  int M, int Nout) {
    constexpr int TM = 128, BK = 32, SR = BK + 8;
    constexpr int NITER = KK / BK;            // 28
    constexpr int WTM = 64, WTN = TN / 2;
    constexpr int MI = WTM / 16, NI = WTN / 16;
    __shared__ ushort Ah[TM * SR], Al[TM * SR];

    const int m0 = blockIdx.y * TM;
    const int n0 = blockIdx.x * TN;
    const int t  = threadIdx.x;
    const int lane = t & 63, w = t >> 6;
    const int wm = w & 1, wn = w >> 1;
    const int lm = lane & 15, lq = lane >> 4;

    const int srow = t >> 1, shalf = t & 1;
    const int b = m0 + srow;
    const bool svalid = (b < M);
    int unode = 0, gnode = 0;
    if (svalid) { unode = userIdx[b]; gnode = itemIdx[b] + USER_NUM; }
    const int sbase = srow * SR + shalf * 16;

    f32x4 acc[MI][NI] = {};

    for (int it = 0; it < NITER; ++it) {
        const int k0 = it * BK;
        {
            float4 v[4] = {};
            if (svalid) {
                int c0 = k0 + shalf * 16;
                int node = (c0 < 448) ? unode : gnode;
                int cc = (c0 < 448) ? c0 : c0 - 448;
                const float* p;
                if (cc < 256)
                    p = (node < USER_NUM) ? uEmbd + (size_t)node * 256 + cc
                                          : iEmbd + (size_t)(node - USER_NUM) * 256 + cc;
                else if (cc < 384) p = f1 + (size_t)node * 128 + (cc - 256);
                else               p = f2 + (size_t)node * 64  + (cc - 384);
#pragma unroll
                for (int q = 0; q < 4; ++q) v[q] = *(const float4*)(p + q * 4);
            }
            ushort hb[16], lb[16];
#pragma unroll
            for (int q = 0; q < 4; ++q) {
                const float av[4] = {v[q].x, v[q].y, v[q].z, v[q].w};
#pragma unroll
                for (int j = 0; j < 4; ++j) split2(av[j], hb[q * 4 + j], lb[q * 4 + j]);
            }
            *(u16x8*)(Ah + sbase)     = *(const u16x8*)&hb[0];
            *(u16x8*)(Ah + sbase + 8) = *(const u16x8*)&hb[8];
            *(u16x8*)(Al + sbase)     = *(const u16x8*)&lb[0];
            *(u16x8*)(Al + sbase + 8) = *(const u16x8*)&lb[8];
        }
        __syncthreads();

        bf16x8 bh[NI], bl[NI];
#pragma unroll
        for (int ni = 0; ni < NI; ++ni) {
            size_t wo = (size_t)(n0 + wn * WTN + ni * 16 + lm) * KK + k0 + lq * 8;
            bh[ni] = *(const bf16x8*)(Wh + wo);
            bl[ni] = *(const bf16x8*)(Wl + wo);
        }
#pragma unroll
        for (int mi = 0; mi < MI; ++mi) {
            int off = (wm * WTM + mi * 16 + lm) * SR + lq * 8;
            bf16x8 ah = *(const bf16x8*)(Ah + off);
            bf16x8 al = *(const bf16x8*)(Al + off);
#pragma unroll
            for (int ni = 0; ni < NI; ++ni) {
                acc[mi][ni] = __builtin_amdgcn_mfma_f32_16x16x32_bf16(ah, bh[ni], acc[mi][ni], 0, 0, 0);
                acc[mi][ni] = __builtin_amdgcn_mfma_f32_16x16x32_bf16(ah, bl[ni], acc[mi][ni], 0, 0, 0);
                acc[mi][ni] = __builtin_amdgcn_mfma_f32_16x16x32_bf16(al, bh[ni], acc[mi][ni], 0, 0, 0);
            }
        }
        __syncthreads();
    }

#pragma unroll
    for (int mi = 0; mi < MI; ++mi)
#pragma unroll
        for (int ni = 0; ni < NI; ++ni)
#pragma unroll
            for (int r = 0; r < 4; ++r) {
                int gm = m0 + wm * WTM + mi * 16 + lq * 4 + r;
                int gn = n0 + wn * WTN + ni * 16 + lm;
                if (gm < M && gn < Nout)
                    C[(size_t)gm * Nout + gn] = fmaxf(acc[mi][ni][r] + bias[gn], 0.f);
            }
}

// ---------------------------------------------------------------------------
// Fused SPMM epilogue (biases pre-folded into G1):
//   out[r,:] = sum_e val_e * H[col_e,:] + G1[r,:]
// 4 rows per 256-thread block, one wave per row; 2-way edge unroll for ILP.
// ---------------------------------------------------------------------------

template <int VEC>
__global__ __launch_bounds__(256)
void spmm_fused(const int* __restrict__ row_ptr, const int* __restrict__ scol,
                const float* __restrict__ sval, const float* __restrict__ H,
                const float* __restrict__ G1, float* __restrict__ out, int n) {
    constexpr int W = 64 * VEC;
    int r = blockIdx.x * 4 + (threadIdx.x >> 6);
    if (r >= n) return;
    int base = (threadIdx.x & 63) * VEC;
    float acc[VEC];
    const float* g = G1 + (size_t)r * W + base;
#pragma unroll
    for (int v = 0; v < VEC; ++v) acc[v] = g[v];
    int e0 = row_ptr[r], e1 = row_ptr[r + 1];
    int e = e0;
    for (; e + 1 < e1; e += 2) {
        int c0 = scol[e], c1 = scol[e + 1];
        float v0 = sval[e], v1 = sval[e + 1];
        const float* h0 = H + (size_t)c0 * W + base;
        const float* h1 = H + (size_t)c1 * W + base;
#pragma unroll
        for (int v = 0; v < VEC; ++v) acc[v] += v0 * h0[v] + v1 * h1[v];
    }
    if (e < e1) {
        int c = scol[e];
        float val = sval[e];
        const float* h = H + (size_t)c * W + base;
#pragma unroll
        for (int v = 0; v < VEC; ++v) acc[v] += val * h[v];
    }
    float* o = out + (size_t)r * W + base;
#pragma unroll
    for (int v = 0; v < VEC; ++v) o[v] = acc[v];
}

// ---------------------------------------------------------------------------
// Fused T2+T3 tail: out[b] = T3_W . relu(T2_W @ e1[b] + T2_b) + T3_b
// ---------------------------------------------------------------------------

__global__ __launch_bounds__(256)
void mlp_tail(const float* __restrict__ e1, const float* __restrict__ T2_W,
              const float* __restrict__ T2_b, const float* __restrict__ T3_W,
              const float* __restrict__ T3_b, float* __restrict__ out, int B) {
    int wid = (blockIdx.x * 256 + threadIdx.x) >> 6;
    if (wid >= B) return;
    int lane = threadIdx.x & 63;
    float s = 0.f;
    if (lane < 32) {
        const float* er = e1 + (size_t)wid * 64;
        const float* wr = T2_W + lane * 64;
        float d = T2_b[lane];
#pragma unroll
        for (int k = 0; k < 64; ++k) d += er[k] * wr[k];
        s = fmaxf(d, 0.f) * T3_W[lane];
    }
#pragma unroll
    for (int off2 = 16; off2 > 0; off2 >>= 1) s += __shfl_down(s, off2);
    if (lane == 0) out[wid] = s + T3_b[0];
}

// ---------------------------------------------------------------------------

extern "C" void kernel_launch(void* const* d_in, const int* in_sizes, int n_in,
                              void* d_out, int out_size, void* d_ws, size_t ws_size,
                              hipStream_t stream) {
    const int* userIdx  = (const int*)d_in[0];
    const int* itemIdx  = (const int*)d_in[1];
    const int* edge_row = (const int*)d_in[2];
    const int* edge_col = (const int*)d_in[3];
    const float* edge_val = (const float*)d_in[4];
    const float* uEmbd  = (const float*)d_in[5];
    const float* iEmbd  = (const float*)d_in[6];
    const float* W1_0 = (const float*)d_in[7];
    const float* b1_0 = (const float*)d_in[8];
    const float* W2_0 = (const float*)d_in[9];
    const float* b2_0 = (const float*)d_in[10];
    const float* W1_1 = (const float*)d_in[11];
    const float* b1_1 = (const float*)d_in[12];
    const float* W2_1 = (const float*)d_in[13];
    const float* b2_1 = (const float*)d_in[14];
    const float* T1_W = (const float*)d_in[15];
    const float* T1_b = (const float*)d_in[16];
    const float* T2_W = (const float*)d_in[17];
    const float* T2_b = (const float*)d_in[18];
    const float* T3_W = (const float*)d_in[19];
    const float* T3_b = (const float*)d_in[20];
    float* out = (float*)d_out;

    const int B   = in_sizes[0];
    const int NNZ = in_sizes[2];
    const int N   = NTOT;

    // ---- workspace carve-up (bytes, 256-aligned) ----
    uint8_t* ws = (uint8_t*)d_ws;
    size_t off = 0;
    auto alloc = [&](size_t bytes) {
        void* p = ws + off;
        off += (bytes + 255) & ~(size_t)255;
        return p;
    };
    float* bufA = (float*)alloc((size_t)N * 128 * 4);  // G1_0; later G1_1 | H_1
    float* bufB = (float*)alloc((size_t)N * 128 * 4);  // H_0;  later f2
    float* f1   = (float*)alloc((size_t)N * 128 * 4);
    float* e1   = (float*)alloc((size_t)B * 64 * 4);
    int*   counts  = (int*)alloc((size_t)2 * N * 4);   // counts[N] + fill[N]
    int*   fill    = counts + N;
    int*   row_ptr = (int*)alloc((size_t)(N + 1) * 4);
    int*   blk_sums= (int*)alloc(128 * 4);
    int*   scol    = (int*)alloc((size_t)NNZ * 4);
    float* sval    = (float*)alloc((size_t)NNZ * 4);
    // pre-split weight matrices (hi/lo bf16 stored as ushort)
    ushort* W10h = (ushort*)alloc(128 * 256 * 2);
    ushort* W10l = (ushort*)alloc(128 * 256 * 2);
    ushort* W20h = (ushort*)alloc(128 * 256 * 2);
    ushort* W20l = (ushort*)alloc(128 * 256 * 2);
    ushort* W11h = (ushort*)alloc(64 * 128 * 2);
    ushort* W11l = (ushort*)alloc(64 * 128 * 2);
    ushort* W21h = (ushort*)alloc(64 * 128 * 2);
    ushort* W21l = (ushort*)alloc(64 * 128 * 2);
    ushort* T1h  = (ushort*)alloc(64 * 896 * 2);
    ushort* T1l  = (ushort*)alloc(64 * 896 * 2);
    (void)ws_size; (void)n_in; (void)out_size;

    float* G1_0 = bufA;
    float* H_0  = bufB;
    float* G1_1 = bufA;
    float* H_1  = bufA + (size_t)N * 64;
    float* f2   = bufB;

    // ---- build CSR ----
    hipMemsetAsync(counts, 0, (size_t)2 * N * 4, stream);
    hist_rows<<<(NNZ + 255) / 256, 256, 0, stream>>>(edge_row, counts, NNZ);
    int nb = (N + 1023) / 1024;   // 98
    scan_block<<<nb, 1024, 0, stream>>>(counts, row_ptr, blk_sums, N);
    scan_sums<<<1, 128, 0, stream>>>(blk_sums, nb);
    scan_add<<<nb, 1024, 0, stream>>>(row_ptr, blk_sums, N, NNZ);
    scatter_edges<<<(NNZ + 255) / 256, 256, 0, stream>>>(edge_row, edge_col, edge_val,
                                                         row_ptr, fill, scol, sval, NNZ);

    // ---- pre-split weights ----
    split_w<<<(32768 + 255) / 256, 256, 0, stream>>>(W1_0, W10h, W10l, 32768);
    split_w<<<(32768 + 255) / 256, 256, 0, stream>>>(W2_0, W20h, W20l, 32768);
    split_w<<<(8192 + 255) / 256, 256, 0, stream>>>(W1_1, W11h, W11l, 8192);
    split_w<<<(8192 + 255) / 256, 256, 0, stream>>>(W2_1, W21h, W21l, 8192);
    split_w<<<(57344 + 255) / 256, 256, 0, stream>>>(T1_W, T1h, T1l, 57344);

    // ---- layer 0: G1_0 = F@W1_0^T (+biases), H_0 = F@W1_0^T + (F*F)@W2_0^T ----
    {
        dim3 grid(2, (N + 127) / 128);   // TN=64, Nout=128
        gemm_dual_direct<64, 256><<<grid, 256, 0, stream>>>(
            uEmbd, iEmbd, USER_NUM, W10h, W10l, W20h, W20l, b1_0, b2_0, G1_0, H_0, N, 128);
    }
    // f1 = spmm(H_0) + G1_0   (biases already in G1_0)
    spmm_fused<2><<<(N + 3) / 4, 256, 0, stream>>>(row_ptr, scol, sval, H_0, G1_0, f1, N);

    // ---- layer 1: G1_1 = f1@W1_1^T (+biases), H_1 = f1@W1_1^T + (f1*f1)@W2_1^T ----
    {
        dim3 grid(1, (N + 127) / 128);   // TN=64, Nout=64
        gemm_dual_direct<64, 128><<<grid, 256, 0, stream>>>(
            f1, f1, N, W11h, W11l, W21h, W21l, b1_1, b2_1, G1_1, H_1, N, 64);
    }
    // f2 = spmm(H_1) + G1_1
    spmm_fused<1><<<(N + 3) / 4, 256, 0, stream>>>(row_ptr, scol, sval, H_1, G1_1, f2, N);

    // ---- fused gather + T1 GEMM, then fused T2+T3 tail ----
    {
        dim3 grid(1, (B + 127) / 128);   // TN=64, K=896
        gemm_t1_mfma<64, 896><<<grid, 256, 0, stream>>>(
            userIdx, itemIdx, uEmbd, iEmbd, f1, f2, T1h, T1l, T1_b, e1, B, 64);
    }
    mlp_tail<<<(B * 64 + 255) / 256, 256, 0, stream>>>(e1, T2_W, T2_b, T3_W, T3_b, out, B);
}

// Round 9
// 461.198 us; speedup vs baseline: 2.0153x; 2.0153x over previous
//
#include <hip/hip_runtime.h>
#include <hip/hip_bf16.h>
#include <cstdint>

#define USER_NUM 30000
#define ITEM_NUM 70000
#define NTOT     100000   // USER_NUM + ITEM_NUM

typedef __attribute__((ext_vector_type(8))) short bf16x8;
typedef __attribute__((ext_vector_type(8))) ushort u16x8;
typedef __attribute__((ext_vector_type(4))) float f32x4;
typedef __attribute__((ext_vector_type(4))) unsigned int u32x4;

// fp32 -> (hi, lo) bf16 pair via truncation; a ~= hi + lo to ~2^-16 rel.
__device__ __forceinline__ void split2(float x, ushort& h, ushort& l) {
    unsigned u = __builtin_bit_cast(unsigned int, x);
    h = (ushort)(u >> 16);
    float hf = __builtin_bit_cast(float, u & 0xffff0000u);
    float lo = x - hf;
    l = (ushort)(__builtin_bit_cast(unsigned int, lo) >> 16);
}

// pack hi16(x0) into low half, hi16(x1) into high half (one v_perm_b32)
__device__ __forceinline__ unsigned int pk_hi(unsigned int x0, unsigned int x1) {
    return __builtin_amdgcn_perm(x1, x0, 0x07060302u);
}

// convert 8 fp32 -> bf16 hi/lo of value and of square (v_perm-packed pairs)
__device__ __forceinline__ void cvt8(const float4& a, const float4& b,
                                     bf16x8& vh, bf16x8& vl, bf16x8& sh, bf16x8& sl) {
    const float f[8] = {a.x, a.y, a.z, a.w, b.x, b.y, b.z, b.w};
    unsigned int ph[4], pl[4], qh[4], ql[4];
#pragma unroll
    for (int p = 0; p < 4; ++p) {
        float f0 = f[2 * p], f1 = f[2 * p + 1];
        unsigned int u0 = __builtin_bit_cast(unsigned int, f0);
        unsigned int u1 = __builtin_bit_cast(unsigned int, f1);
        ph[p] = pk_hi(u0, u1);
        float hf0 = __builtin_bit_cast(float, u0 & 0xffff0000u);
        float hf1 = __builtin_bit_cast(float, u1 & 0xffff0000u);
        pl[p] = pk_hi(__builtin_bit_cast(unsigned int, f0 - hf0),
                      __builtin_bit_cast(unsigned int, f1 - hf1));
        float s0 = f0 * f0, s1 = f1 * f1;
        unsigned int v0 = __builtin_bit_cast(unsigned int, s0);
        unsigned int v1 = __builtin_bit_cast(unsigned int, s1);
        qh[p] = pk_hi(v0, v1);
        float sh0 = __builtin_bit_cast(float, v0 & 0xffff0000u);
        float sh1 = __builtin_bit_cast(float, v1 & 0xffff0000u);
        ql[p] = pk_hi(__builtin_bit_cast(unsigned int, s0 - sh0),
                      __builtin_bit_cast(unsigned int, s1 - sh1));
    }
    vh = __builtin_bit_cast(bf16x8, u32x4{ph[0], ph[1], ph[2], ph[3]});
    vl = __builtin_bit_cast(bf16x8, u32x4{pl[0], pl[1], pl[2], pl[3]});
    sh = __builtin_bit_cast(bf16x8, u32x4{qh[0], qh[1], qh[2], qh[3]});
    sl = __builtin_bit_cast(bf16x8, u32x4{ql[0], ql[1], ql[2], ql[3]});
}

// ---------------------------------------------------------------------------
// CSR build kernels
// ---------------------------------------------------------------------------

__global__ void hist_rows(const int* __restrict__ erow, int* __restrict__ counts, int nnz) {
    int i = blockIdx.x * blockDim.x + threadIdx.x;
    if (i < nnz) atomicAdd(&counts[erow[i]], 1);
}

__global__ void scan_block(const int* __restrict__ counts, int* __restrict__ row_ptr,
                           int* __restrict__ blk_sums, int n) {
    __shared__ int sd[1024];
    int i = blockIdx.x * 1024 + threadIdx.x;
    int v = (i < n) ? counts[i] : 0;
    sd[threadIdx.x] = v;
    __syncthreads();
    for (int off = 1; off < 1024; off <<= 1) {
        int t = (threadIdx.x >= off) ? sd[threadIdx.x - off] : 0;
        __syncthreads();
        sd[threadIdx.x] += t;
        __syncthreads();
    }
    if (i < n) row_ptr[i] = sd[threadIdx.x] - v;   // block-local exclusive
    if (threadIdx.x == 1023) blk_sums[blockIdx.x] = sd[1023];
}

__global__ void scan_sums(int* __restrict__ blk_sums, int nb) {
    __shared__ int sd[128];
    int v = (threadIdx.x < nb) ? blk_sums[threadIdx.x] : 0;
    sd[threadIdx.x] = v;
    __syncthreads();
    for (int off = 1; off < 128; off <<= 1) {
        int t = (threadIdx.x >= off) ? sd[threadIdx.x - off] : 0;
        __syncthreads();
        sd[threadIdx.x] += t;
        __syncthreads();
    }
    if (threadIdx.x < nb) blk_sums[threadIdx.x] = sd[threadIdx.x] - v;  // exclusive
}

__global__ void scan_add(int* __restrict__ row_ptr, const int* __restrict__ blk_sums,
                         int n, int nnz) {
    int i = blockIdx.x * 1024 + threadIdx.x;
    if (i < n) row_ptr[i] += blk_sums[blockIdx.x];
    if (blockIdx.x == 0 && threadIdx.x == 0) row_ptr[n] = nnz;
}

__global__ void scatter_edges(const int* __restrict__ erow, const int* __restrict__ ecol,
                              const float* __restrict__ eval,
                              const int* __restrict__ row_ptr, int* __restrict__ fill,
                              int* __restrict__ scol, float* __restrict__ sval, int nnz) {
    int i = blockIdx.x * blockDim.x + threadIdx.x;
    if (i >= nnz) return;
    int r = erow[i];
    int pos = row_ptr[r] + atomicAdd(&fill[r], 1);
    scol[pos] = ecol[i];
    sval[pos] = eval[i];
}

// ---------------------------------------------------------------------------
// Pre-split a weight matrix into hi/lo bf16 arrays (done once per launch).
// ---------------------------------------------------------------------------

__global__ void split_w(const float* __restrict__ W, ushort* __restrict__ Wh,
                        ushort* __restrict__ Wl, int n) {
    int i = blockIdx.x * blockDim.x + threadIdx.x;
    if (i >= n) return;
    ushort h, l;
    split2(W[i], h, l);
    Wh[i] = h;
    Wl[i] = l;
}

// ---------------------------------------------------------------------------
// Dual split-bf16 MFMA GEMM, v3 (R4 2-barrier skeleton + W-in-LDS + raw-A):
//   C1 = A @ W1^T + b1 + b2 ;  C2 = (A @ W1^T) + (A*A) @ W2^T
// A = virtual row-concat [xa ; xb] split at `split`, rows length KK.
// TM=128, block 256 = 4 waves, wave tile 32 rows x TN (row-exclusive). BK=32.
// Per iter: A-tile staged RAW fp32 (18 KB, padded SR=36) + W tiles staged
// bf16 (4 arrays, padded SR=40, 20.5 KB) cooperatively -> barrier -> each
// wave reads its own rows, converts hi/lo + square in regs (v_perm-packed),
// reads W fragments from LDS, MFMAs. LDS 38.9 KB -> 4 blocks/CU.
// Cuts L2 W-traffic 4x (one staged copy vs per-wave L2 reads) and conversion
// VALU ~2x vs the R4/R6 versions.
// ---------------------------------------------------------------------------

template <int TN, int KK>
__global__ __launch_bounds__(256, 2)
void gemm_dual_mfma(const float* __restrict__ xa, const float* __restrict__ xb, int split,
                    const ushort* __restrict__ W1h, const ushort* __restrict__ W1l,
                    const ushort* __restrict__ W2h, const ushort* __restrict__ W2l,
                    const float* __restrict__ bias1, const float* __restrict__ bias2,
                    float* __restrict__ C1, float* __restrict__ C2,
                    int M, int Nout) {
    constexpr int TM = 128, BK = 32;
    constexpr int SRA = 36;                 // A row stride (floats), 144 B (16-aligned)
    constexpr int SRW = 40;                 // W row stride (ushorts), 80 B (16-aligned)
    constexpr int NITER = KK / BK;
    constexpr int NI = TN / 16;             // 4
    constexpr int MI = 2;                   // 32 rows per wave
    __shared__ float Araw[TM * SRA];        // 18432 B
    __shared__ ushort Wt[4][TN * SRW];      // 20480 B

    const int m0 = blockIdx.y * TM;
    const int n0 = blockIdx.x * TN;
    const int t  = threadIdx.x;
    const int lane = t & 63, w = t >> 6;
    const int lm = lane & 15, lq = lane >> 4;

    // ---- A staging map: thread stages 4 chunks of 16 B (rows t>>3 + 32p, quad t&7)
    const int sarow = t >> 3, saq = t & 7;
    const float* asrc[4];
#pragma unroll
    for (int p = 0; p < 4; ++p) {
        int gm = m0 + sarow + 32 * p;
        const float* rp = xa;
        if (gm < M) rp = (gm < split) ? xa + (size_t)gm * KK
                                      : xb + (size_t)(gm - split) * KK;
        asrc[p] = rp + saq * 4;
    }
    // ---- W staging map: thread stages 1 chunk per array (n = t>>2, quad t&3)
    const int swn = t >> 2, swq = t & 3;
    const ushort* wsrc[4] = {W1h, W1l, W2h, W2l};
    const ushort* wptr[4];
#pragma unroll
    for (int p = 0; p < 4; ++p)
        wptr[p] = wsrc[p] + (size_t)(n0 + swn) * KK + swq * 8;

    f32x4 acc1[MI][NI] = {};
    f32x4 acc2[MI][NI] = {};

    for (int it = 0; it < NITER; ++it) {
        const int k0 = it * BK;
        // ---- stage A raw fp32 ----
#pragma unroll
        for (int p = 0; p < 4; ++p)
            *(float4*)(Araw + (sarow + 32 * p) * SRA + saq * 4) = *(const float4*)(asrc[p] + k0);
        // ---- stage W tiles ----
#pragma unroll
        for (int p = 0; p < 4; ++p)
            *(u32x4*)(Wt[p] + swn * SRW + swq * 8) = *(const u32x4*)(wptr[p] + k0);
        __syncthreads();

#pragma unroll
        for (int mi = 0; mi < MI; ++mi) {
            const int row = w * 32 + mi * 16 + lm;
            const float* ap = Araw + row * SRA + lq * 8;
            float4 x0 = *(const float4*)ap;
            float4 x1 = *(const float4*)(ap + 4);
            bf16x8 vah, val, vqh, vql;
            cvt8(x0, x1, vah, val, vqh, vql);
#pragma unroll
            for (int ni = 0; ni < NI; ++ni) {
                const int woff = (ni * 16 + lm) * SRW + lq * 8;
                bf16x8 b1h = *(const bf16x8*)(Wt[0] + woff);
                bf16x8 b1l = *(const bf16x8*)(Wt[1] + woff);
                bf16x8 b2h = *(const bf16x8*)(Wt[2] + woff);
                bf16x8 b2l = *(const bf16x8*)(Wt[3] + woff);
                acc1[mi][ni] = __builtin_amdgcn_mfma_f32_16x16x32_bf16(vah, b1h, acc1[mi][ni], 0, 0, 0);
                acc1[mi][ni] = __builtin_amdgcn_mfma_f32_16x16x32_bf16(vah, b1l, acc1[mi][ni], 0, 0, 0);
                acc1[mi][ni] = __builtin_amdgcn_mfma_f32_16x16x32_bf16(val, b1h, acc1[mi][ni], 0, 0, 0);
                acc2[mi][ni] = __builtin_amdgcn_mfma_f32_16x16x32_bf16(vqh, b2h, acc2[mi][ni], 0, 0, 0);
                acc2[mi][ni] = __builtin_amdgcn_mfma_f32_16x16x32_bf16(vqh, b2l, acc2[mi][ni], 0, 0, 0);
                acc2[mi][ni] = __builtin_amdgcn_mfma_f32_16x16x32_bf16(vql, b2h, acc2[mi][ni], 0, 0, 0);
            }
        }
        __syncthreads();
    }

    // ---- epilogue: C/D layout col=lane&15, row=lq*4+r; biases folded into C1 ----
#pragma unroll
    for (int mi = 0; mi < MI; ++mi)
#pragma unroll
        for (int ni = 0; ni < NI; ++ni)
#pragma unroll
            for (int r = 0; r < 4; ++r) {
                int gm = m0 + w * 32 + mi * 16 + lq * 4 + r;
                int gn = n0 + ni * 16 + lm;
                if (gm < M && gn < Nout) {
                    size_t o = (size_t)gm * Nout + gn;
                    float g1 = acc1[mi][ni][r];
                    C1[o] = g1 + bias1[gn] + bias2[gn];
                    C2[o] = g1 + acc2[mi][ni][r];
                }
            }
}

// ---------------------------------------------------------------------------
// T1 GEMM with fused gather (known-good R6 structure):
//   e1 = relu( [final[u] ; final[it+U]] @ T1_W^T + T1_b ),  K = 896
// ---------------------------------------------------------------------------

template <int TN, int KK>
__global__ __launch_bounds__(256, 4)
void gemm_t1_mfma(const int* __restrict__ userIdx, const int* __restrict__ itemIdx,
                  const float* __restrict__ uEmbd, const float* __restrict__ iEmbd,
                  const float* __restrict__ f1, const float* __restrict__ f2,
                  const ushort* __restrict__ Wh, const ushort* __restrict__ Wl,
                  const float* __restrict__ bias, float* __restrict__ C,
                  int M, int Nout) {
    constexpr int TM = 128, BK = 32, SR = BK + 8;
    constexpr int NITER = KK / BK;            // 28
    constexpr int WTM = 64, WTN = TN / 2;
    constexpr int MI = WTM / 16, NI = WTN / 16;
    __shared__ ushort Ah[TM * SR], Al[TM * SR];

    const int m0 = blockIdx.y * TM;
    const int n0 = blockIdx.x * TN;
    const int t  = threadIdx.x;
    const int lane = t & 63, w = t >> 6;
    const int wm = w & 1, wn = w >> 1;
    const int lm = lane & 15, lq = lane >> 4;

    const int srow = t >> 1, shalf = t & 1;
    const int b = m0 + srow;
    const bool svalid = (b < M);
    int unode = 0, gnode = 0;
    if (svalid) { unode = userIdx[b]; gnode = itemIdx[b] + USER_NUM; }
    const int sbase = srow * SR + shalf * 16;

    f32x4 acc[MI][NI] = {};

    for (int it = 0; it < NITER; ++it) {
        const int k0 = it * BK;
        {
            float4 v[4] = {};
            if (svalid) {
                int c0 = k0 + shalf * 16;
                int node = (c0 < 448) ? unode : gnode;
                int cc = (c0 < 448) ? c0 : c0 - 448;
                const float* p;
                if (cc < 256)
                    p = (node < USER_NUM) ? uEmbd + (size_t)node * 256 + cc
                                          : iEmbd + (size_t)(node - USER_NUM) * 256 + cc;
                else if (cc < 384) p = f1 + (size_t)node * 128 + (cc - 256);
                else               p = f2 + (size_t)node * 64  + (cc - 384);
#pragma unroll
                for (int q = 0; q < 4; ++q) v[q] = *(const float4*)(p + q * 4);
            }
            ushort hb[16], lb[16];
#pragma unroll
            for (int q = 0; q < 4; ++q) {
                const float av[4] = {v[q].x, v[q].y, v[q].z, v[q].w};
#pragma unroll
                for (int j = 0; j < 4; ++j) split2(av[j], hb[q * 4 + j], lb[q * 4 + j]);
            }
            *(u16x8*)(Ah + sbase)     = *(const u16x8*)&hb[0];
            *(u16x8*)(Ah + sbase + 8) = *(const u16x8*)&hb[8];
            *(u16x8*)(Al + sbase)     = *(const u16x8*)&lb[0];
            *(u16x8*)(Al + sbase + 8) = *(const u16x8*)&lb[8];
        }
        __syncthreads();

        bf16x8 bh[NI], bl[NI];
#pragma unroll
        for (int ni = 0; ni < NI; ++ni) {
            size_t wo = (size_t)(n0 + wn * WTN + ni * 16 + lm) * KK + k0 + lq * 8;
            bh[ni] = *(const bf16x8*)(Wh + wo);
            bl[ni] = *(const bf16x8*)(Wl + wo);
        }
#pragma unroll
        for (int mi = 0; mi < MI; ++mi) {
            int off = (wm * WTM + mi * 16 + lm) * SR + lq * 8;
            bf16x8 ah = *(const bf16x8*)(Ah + off);
            bf16x8 al = *(const bf16x8*)(Al + off);
#pragma unroll
            for (int ni = 0; ni < NI; ++ni) {
                acc[mi][ni] = __builtin_amdgcn_mfma_f32_16x16x32_bf16(ah, bh[ni], acc[mi][ni], 0, 0, 0);
                acc[mi][ni] = __builtin_amdgcn_mfma_f32_16x16x32_bf16(ah, bl[ni], acc[mi][ni], 0, 0, 0);
                acc[mi][ni] = __builtin_amdgcn_mfma_f32_16x16x32_bf16(al, bh[ni], acc[mi][ni], 0, 0, 0);
            }
        }
        __syncthreads();
    }

#pragma unroll
    for (int mi = 0; mi < MI; ++mi)
#pragma unroll
        for (int ni = 0; ni < NI; ++ni)
#pragma unroll
            for (int r = 0; r < 4; ++r) {
                int gm = m0 + wm * WTM + mi * 16 + lq * 4 + r;
                int gn = n0 + wn * WTN + ni * 16 + lm;
                if (gm < M && gn < Nout)
                    C[(size_t)gm * Nout + gn] = fmaxf(acc[mi][ni][r] + bias[gn], 0.f);
            }
}

// ---------------------------------------------------------------------------
// Fused SPMM epilogue (biases pre-folded into G1):
//   out[r,:] = sum_e val_e * H[col_e,:] + G1[r,:]
// 4 rows per 256-thread block, one wave per row; 2-way edge unroll for ILP.
// ---------------------------------------------------------------------------

template <int VEC>
__global__ __launch_bounds__(256)
void spmm_fused(const int* __restrict__ row_ptr, const int* __restrict__ scol,
                const float* __restrict__ sval, const float* __restrict__ H,
                const float* __restrict__ G1, float* __restrict__ out, int n) {
    constexpr int W = 64 * VEC;
    int r = blockIdx.x * 4 + (threadIdx.x >> 6);
    if (r >= n) return;
    int base = (threadIdx.x & 63) * VEC;
    float acc[VEC];
    const float* g = G1 + (size_t)r * W + base;
#pragma unroll
    for (int v = 0; v < VEC; ++v) acc[v] = g[v];
    int e0 = row_ptr[r], e1 = row_ptr[r + 1];
    int e = e0;
    for (; e + 1 < e1; e += 2) {
        int c0 = scol[e], c1 = scol[e + 1];
        float v0 = sval[e], v1 = sval[e + 1];
        const float* h0 = H + (size_t)c0 * W + base;
        const float* h1 = H + (size_t)c1 * W + base;
#pragma unroll
        for (int v = 0; v < VEC; ++v) acc[v] += v0 * h0[v] + v1 * h1[v];
    }
    if (e < e1) {
        int c = scol[e];
        float val = sval[e];
        const float* h = H + (size_t)c * W + base;
#pragma unroll
        for (int v = 0; v < VEC; ++v) acc[v] += val * h[v];
    }
    float* o = out + (size_t)r * W + base;
#pragma unroll
    for (int v = 0; v < VEC; ++v) o[v] = acc[v];
}

// ---------------------------------------------------------------------------
// Fused T2+T3 tail: out[b] = T3_W . relu(T2_W @ e1[b] + T2_b) + T3_b
// ---------------------------------------------------------------------------

__global__ __launch_bounds__(256)
void mlp_tail(const float* __restrict__ e1, const float* __restrict__ T2_W,
              const float* __restrict__ T2_b, const float* __restrict__ T3_W,
              const float* __restrict__ T3_b, float* __restrict__ out, int B) {
    int wid = (blockIdx.x * 256 + threadIdx.x) >> 6;
    if (wid >= B) return;
    int lane = threadIdx.x & 63;
    float s = 0.f;
    if (lane < 32) {
        const float* er = e1 + (size_t)wid * 64;
        const float* wr = T2_W + lane * 64;
        float d = T2_b[lane];
#pragma unroll
        for (int k = 0; k < 64; ++k) d += er[k] * wr[k];
        s = fmaxf(d, 0.f) * T3_W[lane];
    }
#pragma unroll
    for (int off2 = 16; off2 > 0; off2 >>= 1) s += __shfl_down(s, off2);
    if (lane == 0) out[wid] = s + T3_b[0];
}

// ---------------------------------------------------------------------------

extern "C" void kernel_launch(void* const* d_in, const int* in_sizes, int n_in,
                              void* d_out, int out_size, void* d_ws, size_t ws_size,
                              hipStream_t stream) {
    const int* userIdx  = (const int*)d_in[0];
    const int* itemIdx  = (const int*)d_in[1];
    const int* edge_row = (const int*)d_in[2];
    const int* edge_col = (const int*)d_in[3];
    const float* edge_val = (const float*)d_in[4];
    const float* uEmbd  = (const float*)d_in[5];
    const float* iEmbd  = (const float*)d_in[6];
    const float* W1_0 = (const float*)d_in[7];
    const float* b1_0 = (const float*)d_in[8];
    const float* W2_0 = (const float*)d_in[9];
    const float* b2_0 = (const float*)d_in[10];
    const float* W1_1 = (const float*)d_in[11];
    const float* b1_1 = (const float*)d_in[12];
    const float* W2_1 = (const float*)d_in[13];
    const float* b2_1 = (const float*)d_in[14];
    const float* T1_W = (const float*)d_in[15];
    const float* T1_b = (const float*)d_in[16];
    const float* T2_W = (const float*)d_in[17];
    const float* T2_b = (const float*)d_in[18];
    const float* T3_W = (const float*)d_in[19];
    const float* T3_b = (const float*)d_in[20];
    float* out = (float*)d_out;

    const int B   = in_sizes[0];
    const int NNZ = in_sizes[2];
    const int N   = NTOT;

    // ---- workspace carve-up (bytes, 256-aligned) ----
    uint8_t* ws = (uint8_t*)d_ws;
    size_t off = 0;
    auto alloc = [&](size_t bytes) {
        void* p = ws + off;
        off += (bytes + 255) & ~(size_t)255;
        return p;
    };
    float* bufA = (float*)alloc((size_t)N * 128 * 4);  // G1_0; later G1_1 | H_1
    float* bufB = (float*)alloc((size_t)N * 128 * 4);  // H_0;  later f2
    float* f1   = (float*)alloc((size_t)N * 128 * 4);
    float* e1   = (float*)alloc((size_t)B * 64 * 4);
    int*   counts  = (int*)alloc((size_t)2 * N * 4);   // counts[N] + fill[N]
    int*   fill    = counts + N;
    int*   row_ptr = (int*)alloc((size_t)(N + 1) * 4);
    int*   blk_sums= (int*)alloc(128 * 4);
    int*   scol    = (int*)alloc((size_t)NNZ * 4);
    float* sval    = (float*)alloc((size_t)NNZ * 4);
    // pre-split weight matrices (hi/lo bf16 stored as ushort)
    ushort* W10h = (ushort*)alloc(128 * 256 * 2);
    ushort* W10l = (ushort*)alloc(128 * 256 * 2);
    ushort* W20h = (ushort*)alloc(128 * 256 * 2);
    ushort* W20l = (ushort*)alloc(128 * 256 * 2);
    ushort* W11h = (ushort*)alloc(64 * 128 * 2);
    ushort* W11l = (ushort*)alloc(64 * 128 * 2);
    ushort* W21h = (ushort*)alloc(64 * 128 * 2);
    ushort* W21l = (ushort*)alloc(64 * 128 * 2);
    ushort* T1h  = (ushort*)alloc(64 * 896 * 2);
    ushort* T1l  = (ushort*)alloc(64 * 896 * 2);
    (void)ws_size; (void)n_in; (void)out_size;

    float* G1_0 = bufA;
    float* H_0  = bufB;
    float* G1_1 = bufA;
    float* H_1  = bufA + (size_t)N * 64;
    float* f2   = bufB;

    // ---- build CSR ----
    hipMemsetAsync(counts, 0, (size_t)2 * N * 4, stream);
    hist_rows<<<(NNZ + 255) / 256, 256, 0, stream>>>(edge_row, counts, NNZ);
    int nb = (N + 1023) / 1024;   // 98
    scan_block<<<nb, 1024, 0, stream>>>(counts, row_ptr, blk_sums, N);
    scan_sums<<<1, 128, 0, stream>>>(blk_sums, nb);
    scan_add<<<nb, 1024, 0, stream>>>(row_ptr, blk_sums, N, NNZ);
    scatter_edges<<<(NNZ + 255) / 256, 256, 0, stream>>>(edge_row, edge_col, edge_val,
                                                         row_ptr, fill, scol, sval, NNZ);

    // ---- pre-split weights ----
    split_w<<<(32768 + 255) / 256, 256, 0, stream>>>(W1_0, W10h, W10l, 32768);
    split_w<<<(32768 + 255) / 256, 256, 0, stream>>>(W2_0, W20h, W20l, 32768);
    split_w<<<(8192 + 255) / 256, 256, 0, stream>>>(W1_1, W11h, W11l, 8192);
    split_w<<<(8192 + 255) / 256, 256, 0, stream>>>(W2_1, W21h, W21l, 8192);
    split_w<<<(57344 + 255) / 256, 256, 0, stream>>>(T1_W, T1h, T1l, 57344);

    // ---- layer 0: G1_0 = F@W1_0^T (+biases), H_0 = F@W1_0^T + (F*F)@W2_0^T ----
    {
        dim3 grid(2, (N + 127) / 128);   // TN=64, Nout=128
        gemm_dual_mfma<64, 256><<<grid, 256, 0, stream>>>(
            uEmbd, iEmbd, USER_NUM, W10h, W10l, W20h, W20l, b1_0, b2_0, G1_0, H_0, N, 128);
    }
    // f1 = spmm(H_0) + G1_0   (biases already in G1_0)
    spmm_fused<2><<<(N + 3) / 4, 256, 0, stream>>>(row_ptr, scol, sval, H_0, G1_0, f1, N);

    // ---- layer 1: G1_1 = f1@W1_1^T (+biases), H_1 = f1@W1_1^T + (f1*f1)@W2_1^T ----
    {
        dim3 grid(1, (N + 127) / 128);   // TN=64, Nout=64
        gemm_dual_mfma<64, 128><<<grid, 256, 0, stream>>>(
            f1, f1, N, W11h, W11l, W21h, W21l, b1_1, b2_1, G1_1, H_1, N, 64);
    }
    // f2 = spmm(H_1) + G1_1
    spmm_fused<1><<<(N + 3) / 4, 256, 0, stream>>>(row_ptr, scol, sval, H_1, G1_1, f2, N);

    // ---- fused gather + T1 GEMM, then fused T2+T3 tail ----
    {
        dim3 grid(1, (B + 127) / 128);   // TN=64, K=896
        gemm_t1_mfma<64, 896><<<grid, 256, 0, stream>>>(
            userIdx, itemIdx, uEmbd, iEmbd, f1, f2, T1h, T1l, T1_b, e1, B, 64);
    }
    mlp_tail<<<(B * 64 + 255) / 256, 256, 0, stream>>>(e1, T2_W, T2_b, T3_W, T3_b, out, B);
}